// Round 1
// baseline (1660.584 us; speedup 1.0000x reference)
//
#include <hip/hip_runtime.h>
#include <math.h>

#define TID ((int)threadIdx.x)

// ---------- block helpers ----------
struct Shc { float red[8]; float s0; };

template<int NT>
__device__ __forceinline__ float bsum(float v, Shc* sh) {
    #pragma unroll
    for (int off = 32; off; off >>= 1) v += __shfl_down(v, off, 64);
    __syncthreads();                       // protect red[] from previous readers
    if ((TID & 63) == 0) sh->red[TID >> 6] = v;
    __syncthreads();
    float r = 0.f;
    #pragma unroll
    for (int w = 0; w < NT / 64; ++w) r += sh->red[w];
    return r;                              // broadcast, deterministic order
}

template<int NT>
__device__ __forceinline__ float bcast0(float v, Shc* sh) {
    __syncthreads();
    if (TID == 0) sh->s0 = v;
    __syncthreads();
    return sh->s0;
}

// ---------- register-per-thread row ops (dim == NT, element j == TID) ----------
template<int NT>
__device__ __forceinline__ float r_logmap0(float x, Shc* sh) {
    float ss = bsum<NT>(TID == 0 ? 0.f : x * x, sh);
    float x0 = bcast0<NT>(x, sh);
    float d  = acoshf(fmaxf(x0, 1.0f + 1e-7f));
    float sn = sqrtf(fmaxf(ss, 1e-12f));
    return TID == 0 ? 0.f : x * (d / sn);
}

template<int NT>
__device__ __forceinline__ float r_expmap0_projx(float x, Shc* sh) {
    // projx(safe_expmap0(x)); comp0 of input is ignored, comp0 of output from projx
    float ss = bsum<NT>(TID == 0 ? 0.f : x * x, sh);
    float n  = sqrtf(fmaxf(ss, 1e-12f));
    float th = fminf(n, 10.0f);
    float s  = x * (sinhf(th) / n);
    float ss2 = bsum<NT>(TID == 0 ? 0.f : s * s, sh);
    return TID == 0 ? sqrtf(1.0f + ss2) : s;
}

template<int NT>
__device__ __forceinline__ float r_linner(float x, float y, Shc* sh) {
    return bsum<NT>(TID == 0 ? -x * y : x * y, sh);
}

template<int NT>
__device__ __forceinline__ float r_logmap(float x, float y, Shc* sh) {
    float lin  = r_linner<NT>(x, y, sh);
    float beta = fmaxf(-lin, 1.0f + 1e-7f);
    float d    = acoshf(beta);
    float u    = y - beta * x;
    float un2  = r_linner<NT>(u, u, sh);
    float un   = sqrtf(fmaxf(un2, 1e-12f));
    return u * (d / un);
}

template<int NT>
__device__ __forceinline__ float r_expmap_projx(float x, float u, Shc* sh) {
    // projx(safe_expmap(x, u))
    float lin = r_linner<NT>(u, u, sh);
    float n   = sqrtf(fmaxf(lin, 1e-12f));
    float th  = fminf(n, 10.0f);
    float y   = coshf(th) * x + (sinhf(th) / n) * u;
    float ss2 = bsum<NT>(TID == 0 ? 0.f : y * y, sh);
    return TID == 0 ? sqrtf(1.0f + ss2) : y;
}

// ---------- LDS row logmap0 (arbitrary dim, in place) ----------
template<int NT>
__device__ void lds_logmap0(float* row, int dim, Shc* sh) {
    float ss = 0.f;
    for (int j = 1 + TID; j < dim; j += NT) ss += row[j] * row[j];
    ss = bsum<NT>(ss, sh);
    float x0 = row[0];
    float d  = acoshf(fmaxf(x0, 1.0f + 1e-7f));
    float sc = d / sqrtf(fmaxf(ss, 1e-12f));
    __syncthreads();
    for (int j = TID; j < dim; j += NT) row[j] = (j == 0) ? 0.f : row[j] * sc;
    __syncthreads();
}

// ---------- constants ----------
#define NB 1024
#define NSEG 14
#define INP 504
#define ED 128
#define HD 256
#define ROWS (NB * NSEG)

// ---------- K1: normalize + scale + expmap0/projx + logmap0 + enc layer 0 (504->128, EXTRA) ----------
__global__ __launch_bounds__(128) void k_prep_enc0(
    const float* __restrict__ in0, const float* __restrict__ in1,
    const float* __restrict__ in2, const float* __restrict__ in3,
    const float* __restrict__ W0, const float* __restrict__ b0,
    const float* __restrict__ esc, float* __restrict__ z)
{
    __shared__ float u[INP];
    __shared__ Shc sh;
    int blk = blockIdx.x;
    int e = blk / ROWS;
    int r = blk - e * ROWS;
    const float* src = (e == 0 ? in0 : e == 1 ? in1 : e == 2 ? in2 : in3) + (size_t)r * INP;

    float x0v = src[TID];
    float x1v = src[TID + 128];
    float x2v = src[TID + 256];
    float x3v = (TID < 120) ? src[TID + 384] : 0.f;

    // mean / std(ddof=1)
    float s = bsum<128>(x0v + x1v + x2v + x3v, &sh);
    float mu = s / 504.0f;
    x0v -= mu; x1v -= mu; x2v -= mu;
    if (TID < 120) x3v -= mu; else x3v = 0.f;
    float ss = bsum<128>(x0v*x0v + x1v*x1v + x2v*x2v + x3v*x3v, &sh);
    float sd = sqrtf(ss / 503.0f) + 1e-6f;
    float inv = tanhf(esc[0]) / sd;
    x0v *= inv; x1v *= inv; x2v *= inv; x3v *= inv;

    // safe_expmap0 (s excludes element 0)
    float e2 = bsum<128>((TID == 0 ? 0.f : x0v*x0v) + x1v*x1v + x2v*x2v + x3v*x3v, &sh);
    float n = sqrtf(fmaxf(e2, 1e-12f));
    float th = fminf(n, 10.0f);
    float sc1 = sinhf(th) / n;
    if (TID != 0) x0v *= sc1;
    x1v *= sc1; x2v *= sc1; x3v *= sc1;
    // projx comp0 needs fresh sum of squares of stored s
    float e3 = bsum<128>((TID == 0 ? 0.f : x0v*x0v) + x1v*x1v + x2v*x2v + x3v*x3v, &sh);
    float h0 = sqrtf(1.0f + e3);
    // logmap0
    float d = acoshf(fmaxf(h0, 1.0f + 1e-7f));
    float sc2 = d / sqrtf(fmaxf(e3, 1e-12f));
    u[TID] = (TID == 0) ? 0.f : x0v * sc2;
    u[TID + 128] = x1v * sc2;
    u[TID + 256] = x2v * sc2;
    if (TID < 120) u[TID + 384] = x3v * sc2;
    __syncthreads();

    // y = u @ W0[e] + b0[e]   (u[0] == 0, skip j = 0)
    const float* w = W0 + (size_t)e * INP * ED;
    float y = b0[e * ED + TID];
    #pragma unroll 8
    for (int j = 1; j < INP; ++j) y += u[j] * w[(size_t)j * ED + TID];

    y = r_expmap0_projx<128>(y, &sh);
    y = r_logmap0<128>(y, &sh);       // EXTRA (i < nl-1)
    y = r_expmap0_projx<128>(y, &sh);
    z[(size_t)blk * ED + TID] = y;
}

// ---------- K2: enc layer 128->128 (in place) ----------
template<bool EXTRA>
__global__ __launch_bounds__(128) void k_enc_layer(
    float* __restrict__ z, const float* __restrict__ W, const float* __restrict__ b)
{
    __shared__ float u[ED];
    __shared__ Shc sh;
    int blk = blockIdx.x;
    int e = blk / ROWS;
    float x = z[(size_t)blk * ED + TID];
    x = r_logmap0<128>(x, &sh);
    u[TID] = x;
    __syncthreads();
    const float* w = W + (size_t)e * ED * ED;
    float y = b[e * ED + TID];
    #pragma unroll 8
    for (int j = 0; j < ED; ++j) y += u[j] * w[j * ED + TID];
    y = r_expmap0_projx<128>(y, &sh);
    if (EXTRA) {
        y = r_logmap0<128>(y, &sh);
        y = r_expmap0_projx<128>(y, &sh);
    }
    z[(size_t)blk * ED + TID] = y;
}

// ---------- K3/K4: frechet mean over npts points of dim 128 ----------
__global__ __launch_bounds__(128) void k_frechet(
    const float* __restrict__ src, size_t blk_stride, size_t p_stride, int npts,
    float* __restrict__ dst)
{
    __shared__ float pts[NSEG][ED];
    __shared__ Shc sh;
    const float* base = src + (size_t)blockIdx.x * blk_stride;
    for (int p = 0; p < npts; ++p) pts[p][TID] = base[(size_t)p * p_stride + TID];
    __syncthreads();
    float acc = 0.f;
    for (int p = 0; p < npts; ++p) acc += r_logmap0<128>(pts[p][TID], &sh);
    acc = acc / (float)npts;
    float cur = r_expmap0_projx<128>(acc, &sh);
    for (int it = 0; it < 10; ++it) {
        float vs = 0.f;
        for (int p = 0; p < npts; ++p) vs += r_logmap<128>(cur, pts[p][TID], &sh);
        vs = (vs / (float)npts) * 0.5f;
        cur = r_expmap_projx<128>(cur, vs, &sh);
    }
    dst[(size_t)blockIdx.x * ED + TID] = cur;
}

// ---------- decode: v_h = projx(safe_expmap0(logmap(x_prev, z_last))) ----------
__global__ __launch_bounds__(128) void k_vh(
    const float* __restrict__ xp, const float* __restrict__ zl, float* __restrict__ vh)
{
    __shared__ Shc sh;
    size_t i = (size_t)blockIdx.x * ED + TID;
    float v = r_logmap<128>(xp[i], zl[i], &sh);
    v = r_expmap0_projx<128>(v, &sh);
    vh[i] = v;
}

// ---------- generic hyperbolic MLP layer ----------
template<int IN, int OUT, bool EXTRA, bool FINAL_LOG>
__global__ __launch_bounds__(OUT) void k_mlp(
    const float* __restrict__ src, const float* __restrict__ W, const float* __restrict__ b,
    float* __restrict__ dst)
{
    __shared__ float u[IN];
    __shared__ Shc sh;
    int bx = blockIdx.x;
    for (int j = TID; j < IN; j += OUT) u[j] = src[(size_t)bx * IN + j];
    __syncthreads();
    lds_logmap0<OUT>(u, IN, &sh);
    float y = b[TID];
    #pragma unroll 8
    for (int j = 0; j < IN; ++j) y += u[j] * W[j * OUT + TID];
    y = r_expmap0_projx<OUT>(y, &sh);
    if (EXTRA) {
        y = r_logmap0<OUT>(y, &sh);
        y = r_expmap0_projx<OUT>(y, &sh);
    }
    if (FINAL_LOG) y = r_logmap0<OUT>(y, &sh);
    dst[(size_t)bx * OUT + TID] = y;
}

// ---------- decode: z_up / z_next ----------
__global__ __launch_bounds__(128) void k_zstep(
    const float* __restrict__ zl, const float* __restrict__ vtr,
    const float* __restrict__ step_p, const float* __restrict__ alpha_p,
    float* __restrict__ znext)
{
    __shared__ Shc sh;
    size_t i = (size_t)blockIdx.x * ED + TID;
    float step = 1.0f / (1.0f + expf(-step_p[0]));
    float a    = 1.0f / (1.0f + expf(-alpha_p[0]));
    float zlv  = zl[i];
    float zu = r_expmap_projx<128>(zlv, step * vtr[i], &sh);
    float lg = r_logmap<128>(zlv, zu, &sh);
    float zn = r_expmap_projx<128>(zlv, (1.0f - a) * lg, &sh);
    znext[i] = zn;
}

// ---------- decode head: logmap0 -> dec_W0 -> LN -> gelu -> dec_W1 -> out ----------
__global__ __launch_bounds__(256) void k_dec(
    const float* __restrict__ zn, const float* __restrict__ W0, const float* __restrict__ b0,
    const float* __restrict__ ln_g, const float* __restrict__ ln_b,
    const float* __restrict__ W1, const float* __restrict__ b1,
    float* __restrict__ out, int step)
{
    __shared__ float u[ED];
    __shared__ float tl[HD];
    __shared__ Shc sh;
    int bx = blockIdx.x;
    for (int j = TID; j < ED; j += HD) u[j] = zn[(size_t)bx * ED + j];
    __syncthreads();
    lds_logmap0<256>(u, ED, &sh);
    float t = b0[TID];
    #pragma unroll 8
    for (int j = 0; j < ED; ++j) t += u[j] * W0[j * HD + TID];
    float m = bsum<256>(t, &sh) * (1.0f / 256.0f);
    float c = t - m;
    float v = bsum<256>(c * c, &sh) * (1.0f / 256.0f);
    t = c / sqrtf(v + 1e-5f) * ln_g[TID] + ln_b[TID];
    t = 0.5f * t * (1.0f + erff(t * 0.70710678118654752f));
    tl[TID] = t;
    __syncthreads();
    float a0 = b1[TID];
    float a1 = (TID < 248) ? b1[TID + 256] : 0.f;
    #pragma unroll 4
    for (int j = 0; j < HD; ++j) {
        float tv = tl[j];
        a0 += tv * W1[j * 504 + TID];
        if (TID < 248) a1 += tv * W1[j * 504 + TID + 256];
    }
    float* o = out + (size_t)bx * 2016 + (size_t)step * 504;
    o[TID] = a0;
    if (TID < 248) o[TID + 256] = a1;
}

// ---------- launch ----------
extern "C" void kernel_launch(void* const* d_in, const int* in_sizes, int n_in,
                              void* d_out, int out_size, void* d_ws, size_t ws_size,
                              hipStream_t stream) {
    const float* trend = (const float*)d_in[0];
    const float* scrs  = (const float*)d_in[1];
    const float* sfin  = (const float*)d_in[2];
    const float* resid = (const float*)d_in[3];
    const float* eW0 = (const float*)d_in[4];
    const float* eb0 = (const float*)d_in[5];
    const float* eW1 = (const float*)d_in[6];
    const float* eb1 = (const float*)d_in[7];
    const float* eW2 = (const float*)d_in[8];
    const float* eb2 = (const float*)d_in[9];
    const float* esc = (const float*)d_in[10];
    const float* dW0 = (const float*)d_in[12];
    const float* db0 = (const float*)d_in[13];
    const float* dW1 = (const float*)d_in[14];
    const float* db1 = (const float*)d_in[15];
    const float* dW2 = (const float*)d_in[16];
    const float* db2 = (const float*)d_in[17];
    const float* alpha_p = (const float*)d_in[18];
    const float* step_p  = (const float*)d_in[19];
    const float* cW0 = (const float*)d_in[20];
    const float* cb0 = (const float*)d_in[21];
    const float* lng = (const float*)d_in[22];
    const float* lnb = (const float*)d_in[23];
    const float* cW1 = (const float*)d_in[24];
    const float* cb1 = (const float*)d_in[25];
    float* outp = (float*)d_out;

    // workspace carve (floats)
    float* w = (float*)d_ws;
    float* zA     = w;                       // 4*1024*14*128 = 7340032
    float* pooled = zA + 7340032;            // 4*1024*128    = 524288
    float* comb   = pooled + 524288;         // 1024*128      = 131072
    float* zb0    = comb + 131072;
    float* zb1    = zb0 + 131072;
    float* zb2    = zb1 + 131072;
    float* vh     = zb2 + 131072;            // 131072
    float* h1     = vh + 131072;             // 1024*256 = 262144
    float* h2     = h1 + 262144;             // 262144
    float* vtr    = h2 + 262144;             // 131072

    const int TOT = 4 * ROWS;                // 57344

    k_prep_enc0<<<TOT, 128, 0, stream>>>(trend, scrs, sfin, resid, eW0, eb0, esc, zA);
    k_enc_layer<true ><<<TOT, 128, 0, stream>>>(zA, eW1, eb1);
    k_enc_layer<false><<<TOT, 128, 0, stream>>>(zA, eW2, eb2);

    // pooled = frechet over NSEG;  combined = frechet over 4 ensembles
    k_frechet<<<4 * NB, 128, 0, stream>>>(zA, (size_t)NSEG * ED, (size_t)ED, NSEG, pooled);
    k_frechet<<<NB, 128, 0, stream>>>(pooled, (size_t)ED, (size_t)NB * ED, 4, comb);

    const float* zl = comb;
    const float* xp = comb;
    float* zbufs[3] = {zb0, zb1, zb2};
    for (int s = 0; s < 4; ++s) {
        float* zn = zbufs[s % 3];
        k_vh<<<NB, 128, 0, stream>>>(xp, zl, vh);
        k_mlp<128, 256, true,  false><<<NB, 256, 0, stream>>>(vh, dW0, db0, h1);
        k_mlp<256, 256, true,  false><<<NB, 256, 0, stream>>>(h1, dW1, db1, h2);
        k_mlp<256, 128, false, true ><<<NB, 128, 0, stream>>>(h2, dW2, db2, vtr);
        k_zstep<<<NB, 128, 0, stream>>>(zl, vtr, step_p, alpha_p, zn);
        k_dec<<<NB, 256, 0, stream>>>(zn, cW0, cb0, lng, lnb, cW1, cb1, outp, s);
        xp = zl;
        zl = zn;
    }
}

// Round 2
// 1057.930 us; speedup vs baseline: 1.5697x; 1.5697x over previous
//
#include <hip/hip_runtime.h>
#include <math.h>

#define TID ((int)threadIdx.x)
#define LANE (TID & 63)

// ---------- constants ----------
#define NB 1024
#define NSEG 14
#define INP 504
#define ED 128
#define HD 256
#define ROWS (NB * NSEG)          // rows per ensemble = 14336
#define NROWS (4 * ROWS)          // 57344

// =======================================================================
// wave-level helpers: one wave (64 lanes) owns one 128-dim row,
// lane holds elements (a = x[lane], b = x[lane+64]). No LDS, no barriers.
// =======================================================================
__device__ __forceinline__ float wsum(float v) {
    #pragma unroll
    for (int off = 32; off; off >>= 1) v += __shfl_xor(v, off, 64);
    return v;
}

__device__ __forceinline__ void p_logmap0(float& a, float& b) {
    float ss = wsum((LANE == 0 ? 0.f : a * a) + b * b);
    float x0 = __shfl(a, 0, 64);
    float d  = acoshf(fmaxf(x0, 1.0f + 1e-7f));
    float sc = d / sqrtf(fmaxf(ss, 1e-12f));
    a = (LANE == 0) ? 0.f : a * sc;
    b *= sc;
}

__device__ __forceinline__ void p_expmap0_projx(float& a, float& b) {
    float ss = wsum((LANE == 0 ? 0.f : a * a) + b * b);
    float n  = sqrtf(fmaxf(ss, 1e-12f));
    float th = fminf(n, 10.0f);
    float sc = sinhf(th) / n;
    float sa = a * sc, sb = b * sc;
    float ss2 = wsum((LANE == 0 ? 0.f : sa * sa) + sb * sb);
    a = (LANE == 0) ? sqrtf(1.0f + ss2) : sa;
    b = sb;
}

__device__ __forceinline__ float p_linner(float xa, float xb, float ya, float yb) {
    return wsum((LANE == 0 ? -xa * ya : xa * ya) + xb * yb);
}

__device__ __forceinline__ void p_logmap(float xa, float xb, float ya, float yb,
                                         float& oa, float& ob) {
    float lin  = p_linner(xa, xb, ya, yb);
    float beta = fmaxf(-lin, 1.0f + 1e-7f);
    float d    = acoshf(beta);
    float ua = ya - beta * xa, ub = yb - beta * xb;
    float un2 = p_linner(ua, ub, ua, ub);
    float sc  = d / sqrtf(fmaxf(un2, 1e-12f));
    oa = ua * sc; ob = ub * sc;
}

__device__ __forceinline__ void p_expmap_projx(float& xa, float& xb, float ua, float ub) {
    float lin = p_linner(ua, ub, ua, ub);
    float n   = sqrtf(fmaxf(lin, 1e-12f));
    float th  = fminf(n, 10.0f);
    float ch  = coshf(th), sh = sinhf(th) / n;
    float ya = ch * xa + sh * ua;
    float yb = ch * xb + sh * ub;
    float ss2 = wsum((LANE == 0 ? 0.f : ya * ya) + yb * yb);
    xa = (LANE == 0) ? sqrtf(1.0f + ss2) : ya;
    xb = yb;
}

// =======================================================================
// block-level helpers (for k_mlp / k_dec where dim == blockDim)
// =======================================================================
struct Shc { float red[8]; float s0; };

template<int NT>
__device__ __forceinline__ float bsum(float v, Shc* sh) {
    #pragma unroll
    for (int off = 32; off; off >>= 1) v += __shfl_down(v, off, 64);
    __syncthreads();
    if ((TID & 63) == 0) sh->red[TID >> 6] = v;
    __syncthreads();
    float r = 0.f;
    #pragma unroll
    for (int w = 0; w < NT / 64; ++w) r += sh->red[w];
    return r;
}

template<int NT>
__device__ __forceinline__ float bcast0(float v, Shc* sh) {
    __syncthreads();
    if (TID == 0) sh->s0 = v;
    __syncthreads();
    return sh->s0;
}

template<int NT>
__device__ __forceinline__ float r_logmap0(float x, Shc* sh) {
    float ss = bsum<NT>(TID == 0 ? 0.f : x * x, sh);
    float x0 = bcast0<NT>(x, sh);
    float d  = acoshf(fmaxf(x0, 1.0f + 1e-7f));
    float sn = sqrtf(fmaxf(ss, 1e-12f));
    return TID == 0 ? 0.f : x * (d / sn);
}

template<int NT>
__device__ __forceinline__ float r_expmap0_projx(float x, Shc* sh) {
    float ss = bsum<NT>(TID == 0 ? 0.f : x * x, sh);
    float n  = sqrtf(fmaxf(ss, 1e-12f));
    float th = fminf(n, 10.0f);
    float s  = x * (sinhf(th) / n);
    float ss2 = bsum<NT>(TID == 0 ? 0.f : s * s, sh);
    return TID == 0 ? sqrtf(1.0f + ss2) : s;
}

template<int NT>
__device__ void lds_logmap0(float* row, int dim, Shc* sh) {
    float ss = 0.f;
    for (int j = 1 + TID; j < dim; j += NT) ss += row[j] * row[j];
    ss = bsum<NT>(ss, sh);
    float x0 = row[0];
    float d  = acoshf(fmaxf(x0, 1.0f + 1e-7f));
    float sc = d / sqrtf(fmaxf(ss, 1e-12f));
    __syncthreads();
    for (int j = TID; j < dim; j += NT) row[j] = (j == 0) ? 0.f : row[j] * sc;
    __syncthreads();
}

// =======================================================================
// K_prep_stats: per row compute affine coeffs A,B s.t. u[j>=1] = A*x[j]+B
// (normalize + tanh-scale + expmap0 + projx + logmap0 collapses to affine)
// one wave per row, 8 elems/lane over the 504-dim row.
// =======================================================================
__global__ __launch_bounds__(256) void k_prep_stats(
    const float* __restrict__ i0, const float* __restrict__ i1,
    const float* __restrict__ i2, const float* __restrict__ i3,
    const float* __restrict__ esc, float* __restrict__ rowAB)
{
    int row = blockIdx.x * 4 + (TID >> 6);
    int e = row / ROWS;
    int r = row - e * ROWS;
    const float* src = (e == 0 ? i0 : e == 1 ? i1 : e == 2 ? i2 : i3) + (size_t)r * INP;

    float x[8];
    #pragma unroll
    for (int t = 0; t < 7; ++t) x[t] = src[64 * t + LANE];
    x[7] = (LANE < 56) ? src[448 + LANE] : 0.f;

    float s = 0.f;
    #pragma unroll
    for (int t = 0; t < 8; ++t) s += x[t];
    s = wsum(s);
    float mu = s * (1.0f / 504.0f);
    #pragma unroll
    for (int t = 0; t < 7; ++t) x[t] -= mu;
    x[7] = (LANE < 56) ? x[7] - mu : 0.f;

    float ss = 0.f;
    #pragma unroll
    for (int t = 0; t < 8; ++t) ss += x[t] * x[t];
    ss = wsum(ss);
    float sd  = sqrtf(ss * (1.0f / 503.0f)) + 1e-6f;
    float inv = tanhf(esc[0]) / sd;

    float x0c = __shfl(x[0], 0, 64);
    float e2 = (ss - x0c * x0c) * inv * inv;      // sum_{j>=1} x_std^2
    float n  = sqrtf(fmaxf(e2, 1e-12f));
    float th = fminf(n, 10.0f);
    float sc1 = sinhf(th) / n;
    float e3 = sc1 * sc1 * e2;
    float h0 = sqrtf(1.0f + e3);
    float d  = acoshf(fmaxf(h0, 1.0f + 1e-7f));
    float sc2 = d / sqrtf(fmaxf(e3, 1e-12f));
    float A = inv * sc1 * sc2;
    float B = -mu * A;
    if (LANE == 0) {
        rowAB[2 * row]     = A;
        rowAB[2 * row + 1] = B;
    }
}

// =======================================================================
// Tiled f32 GEMM: Y[M x 128] = U[M x K] @ W[e][K x 128] + b[e]
// M-tile 64, 256 threads, thread computes 8 rows x 4 cols.
// PREP: U is the raw 4-tensor input; applies u = A*x + B while staging
// (and u[k=0] = 0). Non-PREP may run in place (U == Y): all tile reads
// precede the epilogue writes, and row tiles are disjoint across blocks.
// =======================================================================
template<int K, int KC, bool PREP>
__global__ __launch_bounds__(256) void k_gemm(
    const float* __restrict__ U,
    const float* __restrict__ i0, const float* __restrict__ i1,
    const float* __restrict__ i2, const float* __restrict__ i3,
    const float* __restrict__ rowAB,
    const float* __restrict__ Wg, const float* __restrict__ bg,
    float* __restrict__ Y)
{
    __shared__ float Ut[64][KC];
    __shared__ float Wt[KC][128];
    __shared__ float sA[64], sB[64];

    int row0 = blockIdx.x * 64;
    int e = row0 / ROWS;
    const float* Wp = Wg + (size_t)e * K * 128;

    const float* srcp;
    int rbase;
    if (PREP) {
        srcp = (e == 0 ? i0 : e == 1 ? i1 : e == 2 ? i2 : i3);
        rbase = row0 - e * ROWS;
        if (TID < 64) {
            sA[TID] = rowAB[2 * (row0 + TID)];
            sB[TID] = rowAB[2 * (row0 + TID) + 1];
        }
    } else {
        srcp = U;
        rbase = row0;
    }

    int tc = (TID & 31) * 4;
    int tr = (TID >> 5) * 8;
    float acc[8][4] = {};

    for (int kc = 0; kc < K; kc += KC) {
        __syncthreads();
        // stage U tile (64 x KC)
        for (int idx = TID; idx < 64 * (KC / 4); idx += 256) {
            int r  = idx / (KC / 4);
            int kq = idx - r * (KC / 4);
            float4 v = *(const float4*)&srcp[(size_t)(rbase + r) * K + kc + kq * 4];
            if (PREP) {
                float a = sA[r], bb = sB[r];
                v.x = v.x * a + bb; v.y = v.y * a + bb;
                v.z = v.z * a + bb; v.w = v.w * a + bb;
                if (kc == 0 && kq == 0) v.x = 0.f;   // u[0] = 0
            }
            *(float4*)&Ut[r][kq * 4] = v;
        }
        // stage W tile (KC x 128)
        for (int idx = TID; idx < KC * 32; idx += 256) {
            int k = idx >> 5;
            int c = (idx & 31) * 4;
            *(float4*)&Wt[k][c] = *(const float4*)&Wp[(size_t)(kc + k) * 128 + c];
        }
        __syncthreads();
        for (int k = 0; k < KC; k += 4) {
            float4 b0 = *(const float4*)&Wt[k + 0][tc];
            float4 b1 = *(const float4*)&Wt[k + 1][tc];
            float4 b2 = *(const float4*)&Wt[k + 2][tc];
            float4 b3 = *(const float4*)&Wt[k + 3][tc];
            #pragma unroll
            for (int i = 0; i < 8; ++i) {
                float4 a = *(const float4*)&Ut[tr + i][k];
                acc[i][0] += a.x * b0.x; acc[i][1] += a.x * b0.y; acc[i][2] += a.x * b0.z; acc[i][3] += a.x * b0.w;
                acc[i][0] += a.y * b1.x; acc[i][1] += a.y * b1.y; acc[i][2] += a.y * b1.z; acc[i][3] += a.y * b1.w;
                acc[i][0] += a.z * b2.x; acc[i][1] += a.z * b2.y; acc[i][2] += a.z * b2.z; acc[i][3] += a.z * b2.w;
                acc[i][0] += a.w * b3.x; acc[i][1] += a.w * b3.y; acc[i][2] += a.w * b3.z; acc[i][3] += a.w * b3.w;
            }
        }
    }

    float4 bias = *(const float4*)&bg[e * 128 + tc];
    #pragma unroll
    for (int i = 0; i < 8; ++i) {
        float4 o;
        o.x = acc[i][0] + bias.x; o.y = acc[i][1] + bias.y;
        o.z = acc[i][2] + bias.z; o.w = acc[i][3] + bias.w;
        *(float4*)&Y[(size_t)(row0 + tr + i) * 128 + tc] = o;
    }
}

// =======================================================================
// inter-GEMM row chain: expmap0/projx -> logmap0 -> expmap0/projx -> logmap0
// wave per row, in place.
// =======================================================================
__global__ __launch_bounds__(256) void k_mid(float* __restrict__ Y) {
    int row = blockIdx.x * 4 + (TID >> 6);
    size_t base = (size_t)row * 128;
    float a = Y[base + LANE], b = Y[base + 64 + LANE];
    p_expmap0_projx(a, b);
    p_logmap0(a, b);
    p_expmap0_projx(a, b);
    p_logmap0(a, b);
    Y[base + LANE] = a; Y[base + 64 + LANE] = b;
}

__global__ __launch_bounds__(256) void k_post(float* __restrict__ Y) {
    int row = blockIdx.x * 4 + (TID >> 6);
    size_t base = (size_t)row * 128;
    float a = Y[base + LANE], b = Y[base + 64 + LANE];
    p_expmap0_projx(a, b);
    Y[base + LANE] = a; Y[base + 64 + LANE] = b;
}

// =======================================================================
// frechet mean, one wave per problem, points register-resident
// =======================================================================
template<int NPTS>
__global__ __launch_bounds__(256) void k_frechet_w(
    const float* __restrict__ src, size_t blk_stride, size_t p_stride,
    float* __restrict__ dst)
{
    int prob = blockIdx.x * 4 + (TID >> 6);
    const float* base = src + (size_t)prob * blk_stride;
    float pa[NPTS], pb[NPTS];
    #pragma unroll
    for (int p = 0; p < NPTS; ++p) {
        pa[p] = base[(size_t)p * p_stride + LANE];
        pb[p] = base[(size_t)p * p_stride + 64 + LANE];
    }
    float aa = 0.f, ab = 0.f;
    #pragma unroll
    for (int p = 0; p < NPTS; ++p) {
        float la = pa[p], lb = pb[p];
        p_logmap0(la, lb);
        aa += la; ab += lb;
    }
    aa *= (1.0f / NPTS); ab *= (1.0f / NPTS);
    p_expmap0_projx(aa, ab);
    for (int it = 0; it < 10; ++it) {
        float va = 0.f, vb = 0.f;
        #pragma unroll
        for (int p = 0; p < NPTS; ++p) {
            float oa, ob;
            p_logmap(aa, ab, pa[p], pb[p], oa, ob);
            va += oa; vb += ob;
        }
        va = va * (0.5f / NPTS); vb = vb * (0.5f / NPTS);
        p_expmap_projx(aa, ab, va, vb);
    }
    dst[(size_t)prob * 128 + LANE] = aa;
    dst[(size_t)prob * 128 + 64 + LANE] = ab;
}

// =======================================================================
// decode per-row kernels (wave per row)
// =======================================================================
__global__ __launch_bounds__(256) void k_vh_w(
    const float* __restrict__ xp, const float* __restrict__ zl, float* __restrict__ vh)
{
    int row = blockIdx.x * 4 + (TID >> 6);
    size_t base = (size_t)row * 128;
    float xa = xp[base + LANE], xb = xp[base + 64 + LANE];
    float ya = zl[base + LANE], yb = zl[base + 64 + LANE];
    float oa, ob;
    p_logmap(xa, xb, ya, yb, oa, ob);
    p_expmap0_projx(oa, ob);
    vh[base + LANE] = oa; vh[base + 64 + LANE] = ob;
}

__global__ __launch_bounds__(256) void k_zstep_w(
    const float* __restrict__ zl, const float* __restrict__ vtr,
    const float* __restrict__ step_p, const float* __restrict__ alpha_p,
    float* __restrict__ znext)
{
    int row = blockIdx.x * 4 + (TID >> 6);
    size_t base = (size_t)row * 128;
    float step = 1.0f / (1.0f + expf(-step_p[0]));
    float a    = 1.0f / (1.0f + expf(-alpha_p[0]));
    float za = zl[base + LANE], zb = zl[base + 64 + LANE];
    float ua = step * vtr[base + LANE], ub = step * vtr[base + 64 + LANE];
    float xa = za, xb = zb;
    p_expmap_projx(xa, xb, ua, ub);          // z_up
    float la, lb;
    p_logmap(za, zb, xa, xb, la, lb);
    float na = za, nb = zb;
    p_expmap_projx(na, nb, (1.0f - a) * la, (1.0f - a) * lb);
    znext[base + LANE] = na; znext[base + 64 + LANE] = nb;
}

// ---------- generic hyperbolic MLP layer (block per row) ----------
template<int IN, int OUT, bool EXTRA, bool FINAL_LOG>
__global__ __launch_bounds__(OUT) void k_mlp(
    const float* __restrict__ src, const float* __restrict__ W, const float* __restrict__ b,
    float* __restrict__ dst)
{
    __shared__ float u[IN];
    __shared__ Shc sh;
    int bx = blockIdx.x;
    for (int j = TID; j < IN; j += OUT) u[j] = src[(size_t)bx * IN + j];
    __syncthreads();
    lds_logmap0<OUT>(u, IN, &sh);
    float y = b[TID];
    #pragma unroll 8
    for (int j = 0; j < IN; ++j) y += u[j] * W[j * OUT + TID];
    y = r_expmap0_projx<OUT>(y, &sh);
    if (EXTRA) {
        y = r_logmap0<OUT>(y, &sh);
        y = r_expmap0_projx<OUT>(y, &sh);
    }
    if (FINAL_LOG) y = r_logmap0<OUT>(y, &sh);
    dst[(size_t)bx * OUT + TID] = y;
}

// ---------- decode head ----------
__global__ __launch_bounds__(256) void k_dec(
    const float* __restrict__ zn, const float* __restrict__ W0, const float* __restrict__ b0,
    const float* __restrict__ ln_g, const float* __restrict__ ln_b,
    const float* __restrict__ W1, const float* __restrict__ b1,
    float* __restrict__ out, int step)
{
    __shared__ float u[ED];
    __shared__ float tl[HD];
    __shared__ Shc sh;
    int bx = blockIdx.x;
    for (int j = TID; j < ED; j += HD) u[j] = zn[(size_t)bx * ED + j];
    __syncthreads();
    lds_logmap0<256>(u, ED, &sh);
    float t = b0[TID];
    #pragma unroll 8
    for (int j = 0; j < ED; ++j) t += u[j] * W0[j * HD + TID];
    float m = bsum<256>(t, &sh) * (1.0f / 256.0f);
    float c = t - m;
    float v = bsum<256>(c * c, &sh) * (1.0f / 256.0f);
    t = c / sqrtf(v + 1e-5f) * ln_g[TID] + ln_b[TID];
    t = 0.5f * t * (1.0f + erff(t * 0.70710678118654752f));
    tl[TID] = t;
    __syncthreads();
    float a0 = b1[TID];
    float a1 = (TID < 248) ? b1[TID + 256] : 0.f;
    #pragma unroll 4
    for (int j = 0; j < HD; ++j) {
        float tv = tl[j];
        a0 += tv * W1[j * 504 + TID];
        if (TID < 248) a1 += tv * W1[j * 504 + TID + 256];
    }
    float* o = out + (size_t)bx * 2016 + (size_t)step * 504;
    o[TID] = a0;
    if (TID < 248) o[TID + 256] = a1;
}

// ---------- launch ----------
extern "C" void kernel_launch(void* const* d_in, const int* in_sizes, int n_in,
                              void* d_out, int out_size, void* d_ws, size_t ws_size,
                              hipStream_t stream) {
    const float* trend = (const float*)d_in[0];
    const float* scrs  = (const float*)d_in[1];
    const float* sfin  = (const float*)d_in[2];
    const float* resid = (const float*)d_in[3];
    const float* eW0 = (const float*)d_in[4];
    const float* eb0 = (const float*)d_in[5];
    const float* eW1 = (const float*)d_in[6];
    const float* eb1 = (const float*)d_in[7];
    const float* eW2 = (const float*)d_in[8];
    const float* eb2 = (const float*)d_in[9];
    const float* esc = (const float*)d_in[10];
    const float* dW0 = (const float*)d_in[12];
    const float* db0 = (const float*)d_in[13];
    const float* dW1 = (const float*)d_in[14];
    const float* db1 = (const float*)d_in[15];
    const float* dW2 = (const float*)d_in[16];
    const float* db2 = (const float*)d_in[17];
    const float* alpha_p = (const float*)d_in[18];
    const float* step_p  = (const float*)d_in[19];
    const float* cW0 = (const float*)d_in[20];
    const float* cb0 = (const float*)d_in[21];
    const float* lng = (const float*)d_in[22];
    const float* lnb = (const float*)d_in[23];
    const float* cW1 = (const float*)d_in[24];
    const float* cb1 = (const float*)d_in[25];
    float* outp = (float*)d_out;

    // workspace carve (floats)
    float* w = (float*)d_ws;
    float* Y      = w;                        // 57344*128 = 7,340,032
    float* pooled = Y + 7340032;              // 4*1024*128 = 524,288
    float* comb   = pooled + 524288;          // 131,072
    float* zb0    = comb + 131072;
    float* zb1    = zb0 + 131072;
    float* zb2    = zb1 + 131072;
    float* vh     = zb2 + 131072;             // 131,072 (aliases rowAB)
    float* h1     = vh + 131072;              // 262,144
    float* h2     = h1 + 262144;              // 262,144
    float* vtr    = h2 + 262144;              // 131,072
    float* rowAB  = vh;                       // 57344*2 = 114,688 (enc phase only)

    // ---- encoder ----
    k_prep_stats<<<NROWS / 4, 256, 0, stream>>>(trend, scrs, sfin, resid, esc, rowAB);
    k_gemm<504, 56, true><<<NROWS / 64, 256, 0, stream>>>(
        nullptr, trend, scrs, sfin, resid, rowAB, eW0, eb0, Y);
    k_mid<<<NROWS / 4, 256, 0, stream>>>(Y);
    k_gemm<128, 64, false><<<NROWS / 64, 256, 0, stream>>>(
        Y, nullptr, nullptr, nullptr, nullptr, nullptr, eW1, eb1, Y);
    k_mid<<<NROWS / 4, 256, 0, stream>>>(Y);
    k_gemm<128, 64, false><<<NROWS / 64, 256, 0, stream>>>(
        Y, nullptr, nullptr, nullptr, nullptr, nullptr, eW2, eb2, Y);
    k_post<<<NROWS / 4, 256, 0, stream>>>(Y);

    // ---- frechet pooling ----
    k_frechet_w<NSEG><<<(4 * NB) / 4, 256, 0, stream>>>(Y, (size_t)NSEG * ED, (size_t)ED, pooled);
    k_frechet_w<4><<<NB / 4, 256, 0, stream>>>(pooled, (size_t)ED, (size_t)NB * ED, comb);

    // ---- decode ----
    const float* zl = comb;
    const float* xp = comb;
    float* zbufs[3] = {zb0, zb1, zb2};
    for (int s = 0; s < 4; ++s) {
        float* zn = zbufs[s % 3];
        k_vh_w<<<NB / 4, 256, 0, stream>>>(xp, zl, vh);
        k_mlp<128, 256, true,  false><<<NB, 256, 0, stream>>>(vh, dW0, db0, h1);
        k_mlp<256, 256, true,  false><<<NB, 256, 0, stream>>>(h1, dW1, db1, h2);
        k_mlp<256, 128, false, true ><<<NB, 128, 0, stream>>>(h2, dW2, db2, vtr);
        k_zstep_w<<<NB / 4, 256, 0, stream>>>(zl, vtr, step_p, alpha_p, zn);
        k_dec<<<NB, 256, 0, stream>>>(zn, cW0, cb0, lng, lnb, cW1, cb1, outp, s);
        xp = zl;
        zl = zn;
    }
}

// Round 3
// 691.610 us; speedup vs baseline: 2.4010x; 1.5297x over previous
//
#include <hip/hip_runtime.h>
#include <math.h>

#define TID ((int)threadIdx.x)
#define LANE (TID & 63)

// ---------- constants ----------
#define NB 1024
#define NSEG 14
#define INP 504
#define ED 128
#define HD 256
#define ROWS (NB * NSEG)          // rows per ensemble = 14336
#define NROWS (4 * ROWS)          // 57344

// =======================================================================
// wave helpers
// =======================================================================
__device__ __forceinline__ float wsum1(float v) {
    #pragma unroll
    for (int off = 32; off; off >>= 1) v += __shfl_xor(v, off, 64);
    return v;
}

__device__ __forceinline__ float rdlane(float v, int l) {
    return __int_as_float(__builtin_amdgcn_readlane(__float_as_int(v), l));
}

// element j = t*64 + LANE ; j==0 <=> (t==0 && LANE==0)
template<int E>
__device__ __forceinline__ float wssx(const float* v) {  // sum_{j>=1} v_j^2
    float s = (LANE == 0) ? 0.f : v[0] * v[0];
    #pragma unroll
    for (int t = 1; t < E; ++t) s += v[t] * v[t];
    return wsum1(s);
}

template<int E>
__device__ __forceinline__ float wlinE(const float* x, const float* y) {  // Minkowski
    float s = (LANE == 0) ? -x[0] * y[0] : x[0] * y[0];
    #pragma unroll
    for (int t = 1; t < E; ++t) s += x[t] * y[t];
    return wsum1(s);
}

// safe_expmap0 + projx in place; returns ss2 = sum_{j>=1} out^2
template<int E>
__device__ __forceinline__ float w_exp0(float* v) {
    float ss = wssx<E>(v);
    float n  = sqrtf(fmaxf(ss, 1e-12f));
    float th = fminf(n, 10.0f);
    float sc = sinhf(th) / n;
    #pragma unroll
    for (int t = 0; t < E; ++t) v[t] *= sc;
    float ss2 = sc * sc * ss;
    if (LANE == 0) v[0] = sqrtf(1.0f + ss2);
    return ss2;
}

// logmap0 given known ss2 (comp0 == sqrt(1+ss2))
template<int E>
__device__ __forceinline__ void w_log0k(float* v, float ss2) {
    float x0 = sqrtf(1.0f + ss2);
    float d  = acoshf(fmaxf(x0, 1.0f + 1e-7f));
    float sc = d / sqrtf(fmaxf(ss2, 1e-12f));
    #pragma unroll
    for (int t = 0; t < E; ++t) v[t] *= sc;
    if (LANE == 0) v[0] = 0.f;
}

// full logmap0
template<int E>
__device__ __forceinline__ void w_log0(float* v) {
    float ss = wssx<E>(v);
    float x0 = __shfl(v[0], 0, 64);
    float d  = acoshf(fmaxf(x0, 1.0f + 1e-7f));
    float sc = d / sqrtf(fmaxf(ss, 1e-12f));
    #pragma unroll
    for (int t = 0; t < E; ++t) v[t] *= sc;
    if (LANE == 0) v[0] = 0.f;
}

// =======================================================================
// K_prep_stats: per-row affine coeffs A,B (u[j>=1] = A*x[j]+B)
// =======================================================================
__global__ __launch_bounds__(256) void k_prep_stats(
    const float* __restrict__ i0, const float* __restrict__ i1,
    const float* __restrict__ i2, const float* __restrict__ i3,
    const float* __restrict__ esc, float* __restrict__ rowAB)
{
    int row = blockIdx.x * 4 + (TID >> 6);
    int e = row / ROWS;
    int r = row - e * ROWS;
    const float* src = (e == 0 ? i0 : e == 1 ? i1 : e == 2 ? i2 : i3) + (size_t)r * INP;

    float x[8];
    #pragma unroll
    for (int t = 0; t < 7; ++t) x[t] = src[64 * t + LANE];
    x[7] = (LANE < 56) ? src[448 + LANE] : 0.f;

    float s = 0.f;
    #pragma unroll
    for (int t = 0; t < 8; ++t) s += x[t];
    s = wsum1(s);
    float mu = s * (1.0f / 504.0f);
    #pragma unroll
    for (int t = 0; t < 7; ++t) x[t] -= mu;
    x[7] = (LANE < 56) ? x[7] - mu : 0.f;

    float ss = 0.f;
    #pragma unroll
    for (int t = 0; t < 8; ++t) ss += x[t] * x[t];
    ss = wsum1(ss);
    float sd  = sqrtf(ss * (1.0f / 503.0f)) + 1e-6f;
    float inv = tanhf(esc[0]) / sd;

    float x0c = __shfl(x[0], 0, 64);
    float e2 = (ss - x0c * x0c) * inv * inv;
    float n  = sqrtf(fmaxf(e2, 1e-12f));
    float th = fminf(n, 10.0f);
    float sc1 = sinhf(th) / n;
    float e3 = sc1 * sc1 * e2;
    float h0 = sqrtf(1.0f + e3);
    float d  = acoshf(fmaxf(h0, 1.0f + 1e-7f));
    float sc2 = d / sqrtf(fmaxf(e3, 1e-12f));
    float A = inv * sc1 * sc2;
    float B = -mu * A;
    if (LANE == 0) {
        rowAB[2 * row]     = A;
        rowAB[2 * row + 1] = B;
    }
}

// =======================================================================
// Tiled f32 GEMM (unchanged from R2)
// =======================================================================
template<int K, int KC, bool PREP>
__global__ __launch_bounds__(256) void k_gemm(
    const float* __restrict__ U,
    const float* __restrict__ i0, const float* __restrict__ i1,
    const float* __restrict__ i2, const float* __restrict__ i3,
    const float* __restrict__ rowAB,
    const float* __restrict__ Wg, const float* __restrict__ bg,
    float* __restrict__ Y)
{
    __shared__ float Ut[64][KC];
    __shared__ float Wt[KC][128];
    __shared__ float sA[64], sB[64];

    int row0 = blockIdx.x * 64;
    int e = row0 / ROWS;
    const float* Wp = Wg + (size_t)e * K * 128;

    const float* srcp;
    int rbase;
    if (PREP) {
        srcp = (e == 0 ? i0 : e == 1 ? i1 : e == 2 ? i2 : i3);
        rbase = row0 - e * ROWS;
        if (TID < 64) {
            sA[TID] = rowAB[2 * (row0 + TID)];
            sB[TID] = rowAB[2 * (row0 + TID) + 1];
        }
    } else {
        srcp = U;
        rbase = row0;
    }

    int tc = (TID & 31) * 4;
    int tr = (TID >> 5) * 8;
    float acc[8][4] = {};

    for (int kc = 0; kc < K; kc += KC) {
        __syncthreads();
        for (int idx = TID; idx < 64 * (KC / 4); idx += 256) {
            int r  = idx / (KC / 4);
            int kq = idx - r * (KC / 4);
            float4 v = *(const float4*)&srcp[(size_t)(rbase + r) * K + kc + kq * 4];
            if (PREP) {
                float a = sA[r], bb = sB[r];
                v.x = v.x * a + bb; v.y = v.y * a + bb;
                v.z = v.z * a + bb; v.w = v.w * a + bb;
                if (kc == 0 && kq == 0) v.x = 0.f;
            }
            *(float4*)&Ut[r][kq * 4] = v;
        }
        for (int idx = TID; idx < KC * 32; idx += 256) {
            int k = idx >> 5;
            int c = (idx & 31) * 4;
            *(float4*)&Wt[k][c] = *(const float4*)&Wp[(size_t)(kc + k) * 128 + c];
        }
        __syncthreads();
        for (int k = 0; k < KC; k += 4) {
            float4 b0 = *(const float4*)&Wt[k + 0][tc];
            float4 b1 = *(const float4*)&Wt[k + 1][tc];
            float4 b2 = *(const float4*)&Wt[k + 2][tc];
            float4 b3 = *(const float4*)&Wt[k + 3][tc];
            #pragma unroll
            for (int i = 0; i < 8; ++i) {
                float4 a = *(const float4*)&Ut[tr + i][k];
                acc[i][0] += a.x * b0.x; acc[i][1] += a.x * b0.y; acc[i][2] += a.x * b0.z; acc[i][3] += a.x * b0.w;
                acc[i][0] += a.y * b1.x; acc[i][1] += a.y * b1.y; acc[i][2] += a.y * b1.z; acc[i][3] += a.y * b1.w;
                acc[i][0] += a.z * b2.x; acc[i][1] += a.z * b2.y; acc[i][2] += a.z * b2.z; acc[i][3] += a.z * b2.w;
                acc[i][0] += a.w * b3.x; acc[i][1] += a.w * b3.y; acc[i][2] += a.w * b3.z; acc[i][3] += a.w * b3.w;
            }
        }
    }

    float4 bias = *(const float4*)&bg[e * 128 + tc];
    #pragma unroll
    for (int i = 0; i < 8; ++i) {
        float4 o;
        o.x = acc[i][0] + bias.x; o.y = acc[i][1] + bias.y;
        o.z = acc[i][2] + bias.z; o.w = acc[i][3] + bias.w;
        *(float4*)&Y[(size_t)(row0 + tr + i) * 128 + tc] = o;
    }
}

// =======================================================================
// inter-GEMM row chains (fused analytic: 2 butterflies instead of 8)
// =======================================================================
__global__ __launch_bounds__(256) void k_mid(float* __restrict__ Y) {
    int row = blockIdx.x * 4 + (TID >> 6);
    size_t base = (size_t)row * 128;
    float v[2] = { Y[base + LANE], Y[base + 64 + LANE] };
    float ss2 = w_exp0<2>(v);
    w_log0k<2>(v, ss2);
    ss2 = w_exp0<2>(v);
    w_log0k<2>(v, ss2);
    Y[base + LANE] = v[0]; Y[base + 64 + LANE] = v[1];
}

__global__ __launch_bounds__(256) void k_post(float* __restrict__ Y) {
    int row = blockIdx.x * 4 + (TID >> 6);
    size_t base = (size_t)row * 128;
    float v[2] = { Y[base + LANE], Y[base + 64 + LANE] };
    w_exp0<2>(v);
    Y[base + LANE] = v[0]; Y[base + 64 + LANE] = v[1];
}

// =======================================================================
// frechet mean: batched reductions + lane-distributed transcendentals
// =======================================================================
template<int NPTS>
__global__ __launch_bounds__(256) void k_frechet_w(
    const float* __restrict__ src, size_t blk_stride, size_t p_stride,
    float* __restrict__ dst)
{
    int prob = blockIdx.x * 4 + (TID >> 6);
    const float* base = src + (size_t)prob * blk_stride;
    float pa[NPTS], pb[NPTS];
    #pragma unroll
    for (int p = 0; p < NPTS; ++p) {
        pa[p] = base[(size_t)p * p_stride + LANE];
        pb[p] = base[(size_t)p * p_stride + 64 + LANE];
    }

    // ---- setup: mean of logmap0(points); points on-manifold => Sum s^2 = x0^2-1
    float xp = 1.0f;
    #pragma unroll
    for (int p = 0; p < NPTS; ++p) {
        float x0 = __shfl(pa[p], 0, 64);
        if (LANE == p) xp = x0;
    }
    {
        float bcl = fmaxf(xp, 1.0f + 1e-7f);
        float sq  = sqrtf(fmaxf(bcl * bcl - 1.0f, 1e-12f));
        float dd  = acoshf(bcl);
        xp = dd / sq;                      // c_p in lane p
    }
    float ma = 0.f, mb = 0.f;
    #pragma unroll
    for (int p = 0; p < NPTS; ++p) {
        float cp = rdlane(xp, p);
        ma = fmaf(pa[p], cp, ma);
        mb = fmaf(pb[p], cp, mb);
    }
    if (LANE == 0) ma = 0.f;               // logmap0 comp0 == 0
    ma *= (1.0f / NPTS); mb *= (1.0f / NPTS);
    float cur[2] = { ma, mb };
    w_exp0<2>(cur);
    float ca = cur[0], cb = cur[1];

    // ---- 10 fixed-point iterations
    for (int it = 0; it < 10; ++it) {
        float part[NPTS];
        #pragma unroll
        for (int p = 0; p < NPTS; ++p)
            part[p] = fmaf(cb, pb[p], (LANE == 0) ? -ca * pa[p] : ca * pa[p]);
        #pragma unroll
        for (int off = 32; off; off >>= 1) {
            #pragma unroll
            for (int p = 0; p < NPTS; ++p) part[p] += __shfl_xor(part[p], off, 64);
        }
        // pack lin_p into lane p
        float lp = 0.f;
        #pragma unroll
        for (int p = 0; p < NPTS; ++p) if (LANE == p) lp = part[p];
        float bb  = fmaxf(-lp, 1.0f + 1e-7f);
        float squ = sqrtf(fmaxf(bb * bb - 1.0f, 1e-12f));   // |u| analytic
        float ccv = acoshf(bb) / squ;                        // d/|u|
        float gg  = (LANE < NPTS) ? ccv * bb : 0.f;
        float gv  = wsum1(gg);                               // Sum c_p * beta_p
        float va = 0.f, vb = 0.f;
        #pragma unroll
        for (int p = 0; p < NPTS; ++p) {
            float cp = rdlane(ccv, p);
            va = fmaf(pa[p], cp, va);
            vb = fmaf(pb[p], cp, vb);
        }
        const float sscale = 0.5f / NPTS;
        va = (va - gv * ca) * sscale;
        vb = (vb - gv * cb) * sscale;
        // expmap(cur, v) + projx
        float lin = wsum1(((LANE == 0) ? -va * va : va * va) + vb * vb);
        float n   = sqrtf(fmaxf(lin, 1e-12f));
        float th  = fminf(n, 10.0f);
        float ch  = coshf(th), shn = sinhf(th) / n;
        float ya = ch * ca + shn * va;
        float yb = ch * cb + shn * vb;
        float ss2 = wsum1(((LANE == 0) ? 0.f : ya * ya) + yb * yb);
        ca = (LANE == 0) ? sqrtf(1.0f + ss2) : ya;
        cb = yb;
    }
    dst[(size_t)prob * 128 + LANE] = ca;
    dst[(size_t)prob * 128 + 64 + LANE] = cb;
}

// =======================================================================
// decode row kernels
// =======================================================================
__global__ __launch_bounds__(256) void k_vh_w(
    const float* __restrict__ xp, const float* __restrict__ zl, float* __restrict__ vh)
{
    int row = blockIdx.x * 4 + (TID >> 6);
    size_t base = (size_t)row * 128;
    float x[2] = { xp[base + LANE], xp[base + 64 + LANE] };
    float y[2] = { zl[base + LANE], zl[base + 64 + LANE] };
    float lin  = wlinE<2>(x, y);
    float beta = fmaxf(-lin, 1.0f + 1e-7f);
    float un   = sqrtf(fmaxf(beta * beta - 1.0f, 1e-12f));
    float sc   = acoshf(beta) / un;
    float v[2] = { sc * (y[0] - beta * x[0]), sc * (y[1] - beta * x[1]) };
    w_exp0<2>(v);
    vh[base + LANE] = v[0]; vh[base + 64 + LANE] = v[1];
}

__global__ __launch_bounds__(256) void k_zstep_w(
    const float* __restrict__ zl, const float* __restrict__ vtr,
    const float* __restrict__ step_p, const float* __restrict__ alpha_p,
    float* __restrict__ znext)
{
    int row = blockIdx.x * 4 + (TID >> 6);
    size_t base = (size_t)row * 128;
    float step = 1.0f / (1.0f + expf(-step_p[0]));
    float a    = 1.0f / (1.0f + expf(-alpha_p[0]));
    float z[2] = { zl[base + LANE], zl[base + 64 + LANE] };
    float u[2] = { step * vtr[base + LANE], step * vtr[base + 64 + LANE] };
    // z_up = projx(expmap(z, u))   (u comp0 == 0)
    float lin1 = wlinE<2>(u, u);
    float n1   = sqrtf(fmaxf(lin1, 1e-12f));
    float th1  = fminf(n1, 10.0f);
    float ch1  = coshf(th1), sh1 = sinhf(th1) / n1;
    float zu[2] = { ch1 * z[0] + sh1 * u[0], ch1 * z[1] + sh1 * u[1] };
    float s2 = wsum1(((LANE == 0) ? 0.f : zu[0] * zu[0]) + zu[1] * zu[1]);
    if (LANE == 0) zu[0] = sqrtf(1.0f + s2);
    // lg = logmap(z, z_up);  |lg| = d analytically
    float lin2 = wlinE<2>(z, zu);
    float beta = fmaxf(-lin2, 1.0f + 1e-7f);
    float un   = sqrtf(fmaxf(beta * beta - 1.0f, 1e-12f));
    float d    = acoshf(beta);
    float sc   = d / un;
    float w0 = (1.0f - a) * sc * (zu[0] - beta * z[0]);
    float w1 = (1.0f - a) * sc * (zu[1] - beta * z[1]);
    // z_next = projx(expmap(z, w)); |w|^2 = ((1-a)*d)^2 analytic
    float n3  = sqrtf(fmaxf((1.0f - a) * (1.0f - a) * d * d, 1e-12f));
    float th3 = fminf(n3, 10.0f);
    float ch3 = coshf(th3), sh3 = sinhf(th3) / n3;
    float y0 = ch3 * z[0] + sh3 * w0;
    float y1 = ch3 * z[1] + sh3 * w1;
    float s3 = wsum1(((LANE == 0) ? 0.f : y0 * y0) + y1 * y1);
    if (LANE == 0) y0 = sqrtf(1.0f + s3);
    znext[base + LANE] = y0; znext[base + 64 + LANE] = y1;
}

// =======================================================================
// hyperbolic MLP layer, 4 rows per block (W traffic / 4)
// =======================================================================
template<int IN, int OUT, bool EXTRA, bool FINAL_LOG>
__global__ __launch_bounds__(256) void k_mlp4(
    const float* __restrict__ src, const float* __restrict__ W, const float* __restrict__ b,
    float* __restrict__ dst)
{
    constexpr int EI = IN / 64, EO = OUT / 64;
    __shared__ float u[4][IN];
    __shared__ float yl[4][OUT];
    int w = TID >> 6;
    int row0 = blockIdx.x * 4;

    // phase A: wave-per-row logmap0 -> LDS
    {
        float x[EI];
        #pragma unroll
        for (int t = 0; t < EI; ++t) x[t] = src[(size_t)(row0 + w) * IN + t * 64 + LANE];
        w_log0<EI>(x);
        #pragma unroll
        for (int t = 0; t < EI; ++t) u[w][t * 64 + LANE] = x[t];
    }
    __syncthreads();

    // phase B: GEMM, thread owns one output column (OUT=256: 4 rows; OUT=128: 2 rows)
    constexpr int NR = (OUT == 256) ? 4 : 2;
    int col = (OUT == 256) ? TID : (TID & 127);
    int RB  = (OUT == 256) ? 0 : ((TID >> 7) * 2);
    float acc[NR];
    #pragma unroll
    for (int r = 0; r < NR; ++r) acc[r] = b[col];
    for (int j = 0; j < IN; j += 4) {
        float4 uv[NR];
        #pragma unroll
        for (int r = 0; r < NR; ++r) uv[r] = *(const float4*)&u[RB + r][j];
        float w0 = W[(size_t)(j + 0) * OUT + col];
        float w1 = W[(size_t)(j + 1) * OUT + col];
        float w2 = W[(size_t)(j + 2) * OUT + col];
        float w3 = W[(size_t)(j + 3) * OUT + col];
        #pragma unroll
        for (int r = 0; r < NR; ++r) {
            acc[r] = fmaf(uv[r].x, w0, acc[r]);
            acc[r] = fmaf(uv[r].y, w1, acc[r]);
            acc[r] = fmaf(uv[r].z, w2, acc[r]);
            acc[r] = fmaf(uv[r].w, w3, acc[r]);
        }
    }
    #pragma unroll
    for (int r = 0; r < NR; ++r) yl[RB + r][col] = acc[r];
    __syncthreads();

    // phase C: wave-per-row hyperbolic chain -> dst
    {
        float y[EO];
        #pragma unroll
        for (int t = 0; t < EO; ++t) y[t] = yl[w][t * 64 + LANE];
        float ss2 = w_exp0<EO>(y);
        if (EXTRA) {
            w_log0k<EO>(y, ss2);
            ss2 = w_exp0<EO>(y);
        }
        if (FINAL_LOG) w_log0k<EO>(y, ss2);
        #pragma unroll
        for (int t = 0; t < EO; ++t) dst[(size_t)(row0 + w) * OUT + t * 64 + LANE] = y[t];
    }
}

// =======================================================================
// decode head, 4 rows per block
// =======================================================================
__global__ __launch_bounds__(256) void k_dec4(
    const float* __restrict__ zn, const float* __restrict__ W0, const float* __restrict__ b0,
    const float* __restrict__ ln_g, const float* __restrict__ ln_b,
    const float* __restrict__ W1, const float* __restrict__ b1,
    float* __restrict__ out, int step)
{
    __shared__ float u[4][ED];
    __shared__ float tl[4][HD];
    int w = TID >> 6;
    int row0 = blockIdx.x * 4;

    // phase A: logmap0(zn) -> LDS
    {
        float x[2] = { zn[(size_t)(row0 + w) * ED + LANE],
                       zn[(size_t)(row0 + w) * ED + 64 + LANE] };
        w_log0<2>(x);
        u[w][LANE] = x[0]; u[w][64 + LANE] = x[1];
    }
    __syncthreads();

    // phase B: t = u @ W0 + b0 (col = TID, 4 rows)
    {
        float acc[4];
        #pragma unroll
        for (int r = 0; r < 4; ++r) acc[r] = b0[TID];
        for (int j = 0; j < ED; j += 4) {
            float4 uv[4];
            #pragma unroll
            for (int r = 0; r < 4; ++r) uv[r] = *(const float4*)&u[r][j];
            float w0 = W0[(size_t)(j + 0) * HD + TID];
            float w1 = W0[(size_t)(j + 1) * HD + TID];
            float w2 = W0[(size_t)(j + 2) * HD + TID];
            float w3 = W0[(size_t)(j + 3) * HD + TID];
            #pragma unroll
            for (int r = 0; r < 4; ++r) {
                acc[r] = fmaf(uv[r].x, w0, acc[r]);
                acc[r] = fmaf(uv[r].y, w1, acc[r]);
                acc[r] = fmaf(uv[r].z, w2, acc[r]);
                acc[r] = fmaf(uv[r].w, w3, acc[r]);
            }
        }
        #pragma unroll
        for (int r = 0; r < 4; ++r) tl[r][TID] = acc[r];
    }
    __syncthreads();

    // phase C: LayerNorm + exact GELU, wave-per-row (E=4)
    {
        float tv[4];
        #pragma unroll
        for (int t = 0; t < 4; ++t) tv[t] = tl[w][t * 64 + LANE];
        float s = tv[0] + tv[1] + tv[2] + tv[3];
        float m = wsum1(s) * (1.0f / 256.0f);
        float c[4]; float vs = 0.f;
        #pragma unroll
        for (int t = 0; t < 4; ++t) { c[t] = tv[t] - m; vs += c[t] * c[t]; }
        float var = wsum1(vs) * (1.0f / 256.0f);
        float rstd = 1.0f / sqrtf(var + 1e-5f);
        #pragma unroll
        for (int t = 0; t < 4; ++t) {
            float g = ln_g[t * 64 + LANE], bb = ln_b[t * 64 + LANE];
            float x = c[t] * rstd * g + bb;
            tl[w][t * 64 + LANE] = 0.5f * x * (1.0f + erff(x * 0.70710678118654752f));
        }
    }
    __syncthreads();

    // phase D: out = gelu(t) @ W1 + b1 (cols TID and TID+256, 4 rows)
    {
        bool hi = (TID < 248);
        float acc0[4], acc1[4];
        #pragma unroll
        for (int r = 0; r < 4; ++r) {
            acc0[r] = b1[TID];
            acc1[r] = hi ? b1[TID + 256] : 0.f;
        }
        for (int j = 0; j < HD; j += 4) {
            float4 gv[4];
            #pragma unroll
            for (int r = 0; r < 4; ++r) gv[r] = *(const float4*)&tl[r][j];
            #pragma unroll
            for (int k = 0; k < 4; ++k) {
                float wA = W1[(size_t)(j + k) * 504 + TID];
                float wB = hi ? W1[(size_t)(j + k) * 504 + TID + 256] : 0.f;
                float gk;
                #pragma unroll
                for (int r = 0; r < 4; ++r) {
                    gk = (k == 0) ? gv[r].x : (k == 1) ? gv[r].y : (k == 2) ? gv[r].z : gv[r].w;
                    acc0[r] = fmaf(gk, wA, acc0[r]);
                    acc1[r] = fmaf(gk, wB, acc1[r]);
                }
            }
        }
        #pragma unroll
        for (int r = 0; r < 4; ++r) {
            float* o = out + (size_t)(row0 + r) * 2016 + (size_t)step * 504;
            o[TID] = acc0[r];
            if (hi) o[TID + 256] = acc1[r];
        }
    }
}

// ---------- launch ----------
extern "C" void kernel_launch(void* const* d_in, const int* in_sizes, int n_in,
                              void* d_out, int out_size, void* d_ws, size_t ws_size,
                              hipStream_t stream) {
    const float* trend = (const float*)d_in[0];
    const float* scrs  = (const float*)d_in[1];
    const float* sfin  = (const float*)d_in[2];
    const float* resid = (const float*)d_in[3];
    const float* eW0 = (const float*)d_in[4];
    const float* eb0 = (const float*)d_in[5];
    const float* eW1 = (const float*)d_in[6];
    const float* eb1 = (const float*)d_in[7];
    const float* eW2 = (const float*)d_in[8];
    const float* eb2 = (const float*)d_in[9];
    const float* esc = (const float*)d_in[10];
    const float* dW0 = (const float*)d_in[12];
    const float* db0 = (const float*)d_in[13];
    const float* dW1 = (const float*)d_in[14];
    const float* db1 = (const float*)d_in[15];
    const float* dW2 = (const float*)d_in[16];
    const float* db2 = (const float*)d_in[17];
    const float* alpha_p = (const float*)d_in[18];
    const float* step_p  = (const float*)d_in[19];
    const float* cW0 = (const float*)d_in[20];
    const float* cb0 = (const float*)d_in[21];
    const float* lng = (const float*)d_in[22];
    const float* lnb = (const float*)d_in[23];
    const float* cW1 = (const float*)d_in[24];
    const float* cb1 = (const float*)d_in[25];
    float* outp = (float*)d_out;

    float* w = (float*)d_ws;
    float* Y      = w;                        // 7,340,032
    float* pooled = Y + 7340032;              // 524,288
    float* comb   = pooled + 524288;          // 131,072
    float* zb0    = comb + 131072;
    float* zb1    = zb0 + 131072;
    float* zb2    = zb1 + 131072;
    float* vh     = zb2 + 131072;             // 131,072 (aliases rowAB)
    float* h1     = vh + 131072;              // 262,144
    float* h2     = h1 + 262144;              // 262,144
    float* vtr    = h2 + 262144;              // 131,072
    float* rowAB  = vh;

    // ---- encoder ----
    k_prep_stats<<<NROWS / 4, 256, 0, stream>>>(trend, scrs, sfin, resid, esc, rowAB);
    k_gemm<504, 56, true><<<NROWS / 64, 256, 0, stream>>>(
        nullptr, trend, scrs, sfin, resid, rowAB, eW0, eb0, Y);
    k_mid<<<NROWS / 4, 256, 0, stream>>>(Y);
    k_gemm<128, 64, false><<<NROWS / 64, 256, 0, stream>>>(
        Y, nullptr, nullptr, nullptr, nullptr, nullptr, eW1, eb1, Y);
    k_mid<<<NROWS / 4, 256, 0, stream>>>(Y);
    k_gemm<128, 64, false><<<NROWS / 64, 256, 0, stream>>>(
        Y, nullptr, nullptr, nullptr, nullptr, nullptr, eW2, eb2, Y);
    k_post<<<NROWS / 4, 256, 0, stream>>>(Y);

    // ---- frechet pooling ----
    k_frechet_w<NSEG><<<(4 * NB) / 4, 256, 0, stream>>>(Y, (size_t)NSEG * ED, (size_t)ED, pooled);
    k_frechet_w<4><<<NB / 4, 256, 0, stream>>>(pooled, (size_t)ED, (size_t)NB * ED, comb);

    // ---- decode ----
    const float* zl = comb;
    const float* xp = comb;
    float* zbufs[3] = {zb0, zb1, zb2};
    for (int s = 0; s < 4; ++s) {
        float* zn = zbufs[s % 3];
        k_vh_w<<<NB / 4, 256, 0, stream>>>(xp, zl, vh);
        k_mlp4<128, 256, true,  false><<<NB / 4, 256, 0, stream>>>(vh, dW0, db0, h1);
        k_mlp4<256, 256, true,  false><<<NB / 4, 256, 0, stream>>>(h1, dW1, db1, h2);
        k_mlp4<256, 128, false, true ><<<NB / 4, 256, 0, stream>>>(h2, dW2, db2, vtr);
        k_zstep_w<<<NB / 4, 256, 0, stream>>>(zl, vtr, step_p, alpha_p, zn);
        k_dec4<<<NB / 4, 256, 0, stream>>>(zn, cW0, cb0, lng, lnb, cW1, cb1, outp, s);
        xp = zl;
        zl = zn;
    }
}